// Round 1
// baseline (518.151 us; speedup 1.0000x reference)
//
#include <hip/hip_runtime.h>
#include <cstdint>
#include <cstddef>

typedef __attribute__((ext_vector_type(8))) __bf16 bf16x8;
typedef __attribute__((ext_vector_type(4))) float floatx4;

// ---------------- weight workspace layout (bf16 elems) ----------------
// m : matrix      K    Nout  T(stride) rows  off
// 0 : Wd1_0       60   128   72        128   0
// 1 : Wd1_1       128  128   136       128   9216
// 2 : Wd1_2       128  128   136       128   26624
// 3 : Wd2_0(remap)188  128   200       128   44032   (k>=60 -> k+4; enc|part1)
// 4 : Wd2_1       128  128   136       128   69632
// 5 : Wd2_2       128  128   136       128   87040
// 6 : Wd2_3(remap)128  129   136       144   104448  (col0 -> row128=blend; col j+1 -> row j)
// 7 : Wc_0 (remap)152  128   168       128   124032  (k>=24 -> k+8; view|feature)
// 8 : Wc_1        128  3     136       16    145536  (rows 3..15 zero)
// total elems = 147712

struct SrcPtrs { const float* p[9]; };

__global__ void prep_zero(unsigned short* __restrict__ ws) {
  uint4* p = (uint4*)ws;
  const int n = 147712 / 8;
  for (int i = blockIdx.x * blockDim.x + threadIdx.x; i < n; i += gridDim.x * blockDim.x)
    p[i] = make_uint4(0u, 0u, 0u, 0u);
}

__global__ void prep_fill(SrcPtrs sp, unsigned short* __restrict__ ws) {
  const int m  = blockIdx.x >> 4;
  const int sl = blockIdx.x & 15;
  const int K[9]  = {60, 128, 128, 188, 128, 128, 128, 152, 128};
  const int N[9]  = {128, 128, 128, 128, 128, 128, 129, 128, 3};
  const int TT[9] = {72, 136, 136, 200, 136, 136, 136, 168, 136};
  const unsigned OFF[9] = {0u, 9216u, 26624u, 44032u, 69632u, 87040u, 104448u, 124032u, 145536u};
  const int Km = K[m], Nm = N[m], Tm = TT[m];
  const float* __restrict__ src = sp.p[m];
  unsigned short* __restrict__ dst = ws + OFF[m];
  const int tot = Km * Nm;
  for (int i = sl * 256 + (int)threadIdx.x; i < tot; i += 16 * 256) {
    int k = i / Nm;
    int n = i - k * Nm;
    int kk = k, row = n;
    if (m == 3 && k >= 60) kk = k + 4;
    if (m == 7 && k >= 24) kk = k + 8;
    if (m == 6) row = (n == 0) ? 128 : (n - 1);
    dst[row * Tm + kk] = __builtin_bit_cast(unsigned short, (__bf16)src[i]);
  }
}

// ---------------- main fused kernel ----------------

__device__ __forceinline__ unsigned pk2(float a, float b) {
  unsigned short ua = __builtin_bit_cast(unsigned short, (__bf16)a);
  unsigned short ub = __builtin_bit_cast(unsigned short, (__bf16)b);
  return (unsigned)ua | ((unsigned)ub << 16);
}

// kind 0: positional enc (k<60: d=k/20, f=(k%20)/2)  kind 1: view enc (k<24: d=3+k/8, f=(k%8)/2)
__device__ __forceinline__ bf16x8 trig_frag(const float* __restrict__ xr, int kb, int kind) {
  bf16x8 r;
#pragma unroll
  for (int p = 0; p < 4; ++p) {
    int k2 = kb + 2 * p;
    int d, f;
    bool valid;
    if (kind == 0) {
      valid = (k2 < 60);
      int dd = k2 / 20;
      d = dd;
      f = (k2 - 20 * dd) >> 1;
    } else {
      valid = (k2 < 24);
      d = 3 + (k2 >> 3);
      f = (k2 & 7) >> 1;
    }
    float v = xr[valid ? d : 0];
    float ang = v * ldexpf(3.14159265358979323846f, f);
    float sn, cs;
    __sincosf(ang, &sn, &cs);
    r[2 * p]     = (__bf16)(valid ? sn : 0.0f);
    r[2 * p + 1] = (__bf16)(valid ? cs : 0.0f);
  }
  return r;
}

// T: Wt row stride (elems). S: k-steps (K_eff = 32*S). STRIG: leading k-steps built from trig.
// KIND: trig kind. NT: output 16-col feature tiles. RELU. OUTM: 0=write B, 1=d23 (B feats + density/blend), 2=c1 (rgb out)
template <int T, int S, int STRIG, int KIND, int NT, bool RELU, int OUTM>
__device__ __forceinline__ void run_layer(const unsigned short* __restrict__ wsrc,
                                          unsigned short* __restrict__ sWt,
                                          unsigned short* __restrict__ sB,
                                          const float* __restrict__ sX,
                                          float* __restrict__ out,
                                          int ptg_base, int tid) {
  const int lane = tid & 63;
  const int w = tid >> 6;      // wave = m-tile (16 points)
  const int q = lane >> 4;
  const int l15 = lane & 15;
  const int pt = w * 16 + l15; // this lane's point row (0..127)

  // 1) preload all activation B-frags (input fully in regs -> in-place update of sB is safe)
  bf16x8 bf[S];
#pragma unroll
  for (int s = 0; s < S; ++s) {
    if (s < STRIG) {
      bf[s] = trig_frag(&sX[pt * 8], s * 32 + q * 8, KIND);
    } else {
      bf[s] = *(const bf16x8*)&sB[pt * 136 + (s - STRIG) * 32 + q * 8];
    }
  }

  // 2) weight chunks through LDS
  constexpr int MAXT_ = (25600 / (2 * T)) / 16;
  constexpr int MAXT = MAXT_ > NT ? NT : MAXT_;
  constexpr int NCH = (NT + MAXT - 1) / MAXT;
#pragma unroll
  for (int c = 0; c < NCH; ++c) {
    const int t0 = c * MAXT;
    const int tc = (NT - t0) < MAXT ? (NT - t0) : MAXT;
    __syncthreads();
    {
      const uint4* __restrict__ src = (const uint4*)(wsrc + t0 * 16 * T);
      uint4* __restrict__ dst = (uint4*)sWt;
      const int n16 = tc * 16 * T / 8;
      for (int i = tid; i < n16; i += 512) dst[i] = src[i];
    }
    __syncthreads();
#pragma unroll
    for (int ntl = 0; ntl < MAXT; ++ntl) {
      if (ntl < tc) {
        const int nt = t0 + ntl;
        floatx4 acc = {0.f, 0.f, 0.f, 0.f};
#pragma unroll
        for (int s = 0; s < S; ++s) {
          bf16x8 af = *(const bf16x8*)&sWt[(ntl * 16 + l15) * T + s * 32 + q * 8];
          acc = __builtin_amdgcn_mfma_f32_16x16x32_bf16(af, bf[s], acc, 0, 0, 0);
        }
        float a0 = acc[0], a1 = acc[1], a2 = acc[2], a3 = acc[3];
        if (RELU) {
          a0 = fmaxf(a0, 0.f); a1 = fmaxf(a1, 0.f);
          a2 = fmaxf(a2, 0.f); a3 = fmaxf(a3, 0.f);
        }
        if (OUTM == 2) {
          // rgb: features q*4+r, valid rows 0..2 -> q==0, acc[0..2]
          if (q == 0) {
            float* o = out + (size_t)(ptg_base + pt) * 5;
            o[0] = a0; o[1] = a1; o[2] = a2;
          }
        } else {
          if (OUTM == 0 || nt < 8) {
            // lane holds 4 consecutive features (nt*16 + q*4 ..): one packed b64 store
            *(uint2*)&sB[pt * 136 + nt * 16 + q * 4] = make_uint2(pk2(a0, a1), pk2(a2, a3));
          }
          if (OUTM == 1 && q == 0) {
            if (nt == 0) out[(size_t)(ptg_base + pt) * 5 + 3] = a0;            // density = feature[:,0]
            if (nt == 8) out[(size_t)(ptg_base + pt) * 5 + 4] =               // blending = sigmoid(dens_out[:,0])
                1.0f / (1.0f + __expf(-a0));
          }
        }
      }
    }
  }
}

__global__ __launch_bounds__(512, 2) void nerf_main(const float* __restrict__ x,
                                                    const unsigned short* __restrict__ ws,
                                                    float* __restrict__ out) {
  __shared__ __align__(16) unsigned short sWt[12800];   // 25600 B weight chunk
  __shared__ __align__(16) unsigned short sB[128 * 136]; // 34816 B activations (row-major, stride 136)
  __shared__ __align__(16) float sX[128 * 8];            // 4096 B  x stash (pos|view)

  const int tid = (int)threadIdx.x;
  const int base = (int)blockIdx.x * 128;

  if (tid < 128) {
    const float* xr = x + (size_t)(base + tid) * 6;
#pragma unroll
    for (int c = 0; c < 6; ++c) sX[tid * 8 + c] = xr[c];
  }
  __syncthreads();

  //            T    S  ST K  NT relu  out
  run_layer< 72, 2, 2, 0, 8, true , 0>(ws + 0u,      sWt, sB, sX, out, base, tid); // d1_0: relu(enc_pos @ W)
  run_layer<136, 4, 0, 0, 8, true , 0>(ws + 9216u,   sWt, sB, sX, out, base, tid); // d1_1
  run_layer<136, 4, 0, 0, 8, false, 0>(ws + 26624u,  sWt, sB, sX, out, base, tid); // d1_2 -> part1 (no relu)
  run_layer<200, 6, 2, 0, 8, true , 0>(ws + 44032u,  sWt, sB, sX, out, base, tid); // d2_0: [enc_pos|part1]
  run_layer<136, 4, 0, 0, 8, true , 0>(ws + 69632u,  sWt, sB, sX, out, base, tid); // d2_1
  run_layer<136, 4, 0, 0, 8, true , 0>(ws + 87040u,  sWt, sB, sX, out, base, tid); // d2_2
  run_layer<136, 4, 0, 0, 9, false, 1>(ws + 104448u, sWt, sB, sX, out, base, tid); // d2_3 -> feature,density,blend
  run_layer<168, 5, 1, 1, 8, true , 0>(ws + 124032u, sWt, sB, sX, out, base, tid); // c_0: [enc_view|feature]
  run_layer<136, 4, 0, 0, 1, false, 2>(ws + 145536u, sWt, sB, sX, out, base, tid); // c_1 -> rgb
}

extern "C" void kernel_launch(void* const* d_in, const int* in_sizes, int n_in,
                              void* d_out, int out_size, void* d_ws, size_t ws_size,
                              hipStream_t stream) {
  (void)n_in; (void)out_size; (void)ws_size;
  const float* x = (const float*)d_in[0];
  SrcPtrs sp;
  for (int i = 0; i < 9; ++i) sp.p[i] = (const float*)d_in[1 + i];
  unsigned short* ws = (unsigned short*)d_ws;
  float* out = (float*)d_out;
  const int N = in_sizes[0] / 6;

  prep_zero<<<64, 256, 0, stream>>>(ws);
  prep_fill<<<144, 256, 0, stream>>>(sp, ws);
  nerf_main<<<N / 128, 512, 0, stream>>>(x, ws, out);
}

// Round 2
// 493.144 us; speedup vs baseline: 1.0507x; 1.0507x over previous
//
#include <hip/hip_runtime.h>
#include <cstdint>
#include <cstddef>

typedef __attribute__((ext_vector_type(8))) __bf16 bf16x8;
typedef __attribute__((ext_vector_type(16))) float floatx16;

struct SrcPtrs { const float* p[9]; };

// ---------------- weight workspace layout (bf16 elems) ----------------
// Rows = output features (A-operand, m). Row length T shorts, 16B-chunk
// XOR-swizzled: logical short kk lives at phys ((kk>>3 ^ (row&7))<<3)|(kk&7).
// m  mat    K    N     T    rows  off      k-remap
// 0  Wd1_0  60   128   64   128   0
// 1  Wd1_1  128  128   128  128   8192
// 2  Wd1_2  128  128   128  128   24576
// 3  Wd2_0  188  128   192  128   40960    k<60 -> 128+k (enc tail), k>=60 -> k-60 (part1 first)
// 4  Wd2_1  128  128   128  128   65536
// 5  Wd2_2  128  128   128  128   81920
// 6  Wd2_3  128  129   128  160   98304    col0 -> row128 (blend), col j+1 -> row j
// 7  Wc_0   152  128   192  128   118784   k<24 -> 128+k (view tail), k>=24 -> k-24 (feature first)
// 8  Wc_1   128  3     128  32    143360   rows 3..31 zero
// total 147456 elems = 294912 B

__global__ void prep_zero(unsigned short* __restrict__ ws) {
  uint4* p = (uint4*)ws;
  const int n = 147456 / 8;
  for (int i = blockIdx.x * blockDim.x + threadIdx.x; i < n; i += gridDim.x * blockDim.x)
    p[i] = make_uint4(0u, 0u, 0u, 0u);
}

__global__ void prep_fill(SrcPtrs sp, unsigned short* __restrict__ ws) {
  const int m  = blockIdx.x >> 4;
  const int sl = blockIdx.x & 15;
  const int K[9]  = {60, 128, 128, 188, 128, 128, 128, 152, 128};
  const int N[9]  = {128, 128, 128, 128, 128, 128, 129, 128, 3};
  const int TT[9] = {64, 128, 128, 192, 128, 128, 128, 192, 128};
  const unsigned OFF[9] = {0u, 8192u, 24576u, 40960u, 65536u, 81920u, 98304u, 118784u, 143360u};
  const int Km = K[m], Nm = N[m], Tm = TT[m];
  const float* __restrict__ src = sp.p[m];
  unsigned short* __restrict__ dst = ws + OFF[m];
  const int tot = Km * Nm;
  for (int i = sl * 256 + (int)threadIdx.x; i < tot; i += 16 * 256) {
    int k = i / Nm;
    int n = i - k * Nm;
    int kk = k, row = n;
    if (m == 3) kk = (k < 60) ? 128 + k : k - 60;
    if (m == 7) kk = (k < 24) ? 128 + k : k - 24;
    if (m == 6) row = (n == 0) ? 128 : n - 1;
    int c = (kk >> 3) ^ (row & 7);
    int phys = (c << 3) | (kk & 7);
    dst[row * Tm + phys] = __builtin_bit_cast(unsigned short, (__bf16)src[i]);
  }
}

// ---------------- main fused kernel ----------------

__device__ __forceinline__ unsigned pk2(float a, float b) {
  unsigned short ua = __builtin_bit_cast(unsigned short, (__bf16)a);
  unsigned short ub = __builtin_bit_cast(unsigned short, (__bf16)b);
  return (unsigned)ua | ((unsigned)ub << 16);
}

// KIND 0: positional enc (k2<60: d=k2/20, f=(k2%20)>>1)
// KIND 1: view enc       (k2<24: d=3+k2/8, f=(k2%8)>>1)
// element j: k2 = kb+j; even->sin, odd->cos (d-blocks have even length so parity decode works)
template <int KIND>
__device__ __forceinline__ bf16x8 trig_frag(const float* __restrict__ xr, int kb) {
  bf16x8 r;
#pragma unroll
  for (int j = 0; j < 8; ++j) {
    int k2 = kb + j;
    int d, f;
    bool valid;
    if (KIND == 0) {
      valid = (k2 < 60);
      int dd = k2 / 20;
      d = dd;
      f = (k2 - 20 * dd) >> 1;
    } else {
      valid = (k2 < 24);
      d = 3 + (k2 >> 3);
      f = (k2 & 7) >> 1;
    }
    float v = xr[valid ? d : 0];
    float ang = v * ldexpf(3.14159265358979323846f, f);
    float sn, cs;
    __sincosf(ang, &sn, &cs);
    float val = (k2 & 1) ? cs : sn;
    r[j] = (__bf16)(valid ? val : 0.0f);
  }
  return r;
}

// 32x32x16 bf16 MFMA, operand swap: A = weights (m=feature), B = activations (n=point).
// A[m=lane&31][k=(lane>>5)*8+j], B[k=(lane>>5)*8+j][n=lane&31],
// C/D: col(point)=lane&31, row(feature)=(reg&3)+8*(reg>>2)+4*(lane>>5).
// T: weight row stride (shorts, multiple of 32). SL: k-steps (of 16) read from sB.
// ST: trailing trig k-steps. NT: 32-feature output tiles. OUTM: 0=write sB, 1=d2_3, 2=c_1.
template <int T, int SL, int ST, int KIND, int NT, bool RELU, int OUTM>
__device__ __forceinline__ void run_layer(const unsigned short* __restrict__ wsrc,
                                          unsigned short* __restrict__ sWt,
                                          unsigned short* __restrict__ sB,
                                          const float* __restrict__ sX,
                                          float* __restrict__ out,
                                          int base, int tid) {
  const int lane = tid & 63;
  const int w = tid >> 6;
  const int q2 = lane >> 5;
  const int l31 = lane & 31;
  const int mt = w >> 1;       // 4 m-tiles of 32 points
  const int tl = w & 1;        // which tile of the staged chunk
  const int pt = mt * 32 + l31;
  const int sw = pt & 7;
  constexpr int S = SL + ST;

  __syncthreads();  // previous layer's sB writes visible before preload

  // preload all B-frags for this wave's 32 points (enables in-place sB update)
  bf16x8 bf[S];
#pragma unroll
  for (int s = 0; s < S; ++s) {
    if (s < SL) {
      bf[s] = *(const bf16x8*)&sB[pt * 128 + (((2 * s + q2) ^ sw) << 3)];
    } else {
      bf[s] = trig_frag<KIND>(&sX[pt * 9], (s - SL) * 16 + q2 * 8);
    }
  }

  constexpr int NCH = (NT + 1) / 2;
#pragma unroll
  for (int c = 0; c < NCH; ++c) {
    constexpr int REM_OK = 1;  (void)REM_OK;
    const int tc = (NT - 2 * c) < 2 ? (NT - 2 * c) : 2;
    __syncthreads();  // all waves done reading previous chunk
    {
      const uint4* __restrict__ src = (const uint4*)(wsrc + c * 2 * 32 * T);
      uint4* __restrict__ dst = (uint4*)sWt;
      const int n16 = tc * 32 * T / 8;
      for (int i = tid; i < n16; i += 512) dst[i] = src[i];
    }
    __syncthreads();
    if (tl < tc) {
      const int TILE = 2 * c + tl;
      floatx16 acc;
#pragma unroll
      for (int i = 0; i < 16; ++i) acc[i] = 0.0f;
#pragma unroll
      for (int s = 0; s < S; ++s) {
        bf16x8 af = *(const bf16x8*)&sWt[(tl * 32 + l31) * T + (((2 * s + q2) ^ (l31 & 7)) << 3)];
        acc = __builtin_amdgcn_mfma_f32_32x32x16_bf16(af, bf[s], acc, 0, 0, 0);
      }
      if (OUTM == 2) {
        // rgb rows 0..2 of tile 0: reg 0..2 at q2==0
        if (q2 == 0) {
          float* o = out + (size_t)(base + pt) * 5;
          o[0] = acc[0]; o[1] = acc[1]; o[2] = acc[2];
        }
      } else {
        if (OUTM == 0 || TILE < 4) {
          // lane holds features TILE*32 + 8g + 4*q2 + 0..3 of point pt -> packed uint2 stores
#pragma unroll
          for (int g = 0; g < 4; ++g) {
            float a0 = acc[4 * g], a1 = acc[4 * g + 1], a2 = acc[4 * g + 2], a3 = acc[4 * g + 3];
            if (RELU) {
              a0 = fmaxf(a0, 0.f); a1 = fmaxf(a1, 0.f);
              a2 = fmaxf(a2, 0.f); a3 = fmaxf(a3, 0.f);
            }
            *(uint2*)&sB[pt * 128 + (((TILE * 4 + g) ^ sw) << 3) + 4 * q2] =
                make_uint2(pk2(a0, a1), pk2(a2, a3));
          }
        }
        if (OUTM == 1) {
          if (TILE == 0 && q2 == 0) out[(size_t)(base + pt) * 5 + 3] = acc[0];  // density (raw)
          if (TILE == 4 && q2 == 0)                                              // blending row 128
            out[(size_t)(base + pt) * 5 + 4] = 1.0f / (1.0f + __expf(-acc[0]));
        }
      }
    }
  }
}

__global__ __launch_bounds__(512, 4) void nerf_main(const float* __restrict__ x,
                                                    const unsigned short* __restrict__ ws,
                                                    float* __restrict__ out) {
  __shared__ __align__(16) unsigned short sWt[12288];    // 24576 B: 2 weight tiles of up to T=192
  __shared__ __align__(16) unsigned short sB[128 * 128]; // 32768 B: activations, swizzled rows
  __shared__ float sX[128 * 9];                          // 4608 B: x stash, stride 9

  const int tid = (int)threadIdx.x;
  const int base = (int)blockIdx.x * 128;

  if (tid < 128) {
    const float* xr = x + (size_t)(base + tid) * 6;
#pragma unroll
    for (int c = 0; c < 6; ++c) sX[tid * 9 + c] = xr[c];
  }
  // (first run_layer's leading __syncthreads publishes sX)

  //          T   SL ST K  NT relu  out
  run_layer< 64, 0, 4, 0, 4, true , 0>(ws + 0u,      sWt, sB, sX, out, base, tid); // d1_0
  run_layer<128, 8, 0, 0, 4, true , 0>(ws + 8192u,   sWt, sB, sX, out, base, tid); // d1_1
  run_layer<128, 8, 0, 0, 4, false, 0>(ws + 24576u,  sWt, sB, sX, out, base, tid); // d1_2 -> part1
  run_layer<192, 8, 4, 0, 4, true , 0>(ws + 40960u,  sWt, sB, sX, out, base, tid); // d2_0: [part1|enc_pos]
  run_layer<128, 8, 0, 0, 4, true , 0>(ws + 65536u,  sWt, sB, sX, out, base, tid); // d2_1
  run_layer<128, 8, 0, 0, 4, true , 0>(ws + 81920u,  sWt, sB, sX, out, base, tid); // d2_2
  run_layer<128, 8, 0, 0, 5, false, 1>(ws + 98304u,  sWt, sB, sX, out, base, tid); // d2_3 -> feat,dens,blend
  run_layer<192, 8, 2, 1, 4, true , 0>(ws + 118784u, sWt, sB, sX, out, base, tid); // c_0: [feature|enc_view]
  run_layer<128, 8, 0, 0, 1, false, 2>(ws + 143360u, sWt, sB, sX, out, base, tid); // c_1 -> rgb
}

extern "C" void kernel_launch(void* const* d_in, const int* in_sizes, int n_in,
                              void* d_out, int out_size, void* d_ws, size_t ws_size,
                              hipStream_t stream) {
  (void)n_in; (void)out_size; (void)ws_size;
  const float* x = (const float*)d_in[0];
  SrcPtrs sp;
  for (int i = 0; i < 9; ++i) sp.p[i] = (const float*)d_in[1 + i];
  unsigned short* ws = (unsigned short*)d_ws;
  float* out = (float*)d_out;
  const int N = in_sizes[0] / 6;

  prep_zero<<<72, 256, 0, stream>>>(ws);
  prep_fill<<<144, 256, 0, stream>>>(sp, ws);
  nerf_main<<<N / 128, 512, 0, stream>>>(x, ws, out);
}

// Round 3
// 423.922 us; speedup vs baseline: 1.2223x; 1.1633x over previous
//
#include <hip/hip_runtime.h>
#include <cstdint>
#include <cstddef>

typedef __attribute__((ext_vector_type(8))) __bf16 bf16x8;
typedef __attribute__((ext_vector_type(16))) float floatx16;

struct SrcPtrs { const float* p[9]; };

// ---------------- weight workspace layout (bf16 elems) ----------------
// Rows = output features (A-operand, m). Row length T shorts, 16B-chunk
// XOR-swizzled: logical short kk lives at phys ((kk>>3 ^ (row&7))<<3)|(kk&7).
// m  mat    K    N     T    rows  off      k-remap
// 0  Wd1_0  60   128   64   128   0
// 1  Wd1_1  128  128   128  128   8192
// 2  Wd1_2  128  128   128  128   24576
// 3  Wd2_0  188  128   192  128   40960    k<60 -> 128+k (enc tail), k>=60 -> k-60 (part1 first)
// 4  Wd2_1  128  128   128  128   65536
// 5  Wd2_2  128  128   128  128   81920
// 6  Wd2_3  128  129   128  160   98304    col0 -> row128 (blend), col j+1 -> row j
// 7  Wc_0   152  128   192  128   118784   k<24 -> 128+k (view tail), k>=24 -> k-24 (feature first)
// 8  Wc_1   128  3     128  32    143360   rows 3..31 zero

__global__ void prep_zero(unsigned short* __restrict__ ws) {
  uint4* p = (uint4*)ws;
  const int n = 147456 / 8;
  for (int i = blockIdx.x * blockDim.x + threadIdx.x; i < n; i += gridDim.x * blockDim.x)
    p[i] = make_uint4(0u, 0u, 0u, 0u);
}

__global__ void prep_fill(SrcPtrs sp, unsigned short* __restrict__ ws) {
  const int m  = blockIdx.x >> 4;
  const int sl = blockIdx.x & 15;
  const int K[9]  = {60, 128, 128, 188, 128, 128, 128, 152, 128};
  const int N[9]  = {128, 128, 128, 128, 128, 128, 129, 128, 3};
  const int TT[9] = {64, 128, 128, 192, 128, 128, 128, 192, 128};
  const unsigned OFF[9] = {0u, 8192u, 24576u, 40960u, 65536u, 81920u, 98304u, 118784u, 143360u};
  const int Km = K[m], Nm = N[m], Tm = TT[m];
  const float* __restrict__ src = sp.p[m];
  unsigned short* __restrict__ dst = ws + OFF[m];
  const int tot = Km * Nm;
  for (int i = sl * 256 + (int)threadIdx.x; i < tot; i += 16 * 256) {
    int k = i / Nm;
    int n = i - k * Nm;
    int kk = k, row = n;
    if (m == 3) kk = (k < 60) ? 128 + k : k - 60;
    if (m == 7) kk = (k < 24) ? 128 + k : k - 24;
    if (m == 6) row = (n == 0) ? 128 : n - 1;
    int c = (kk >> 3) ^ (row & 7);
    int phys = (c << 3) | (kk & 7);
    dst[row * Tm + phys] = __builtin_bit_cast(unsigned short, (__bf16)src[i]);
  }
}

// ---------------- main fused kernel ----------------

__device__ __forceinline__ unsigned pk2(float a, float b) {
  unsigned short ua = __builtin_bit_cast(unsigned short, (__bf16)a);
  unsigned short ub = __builtin_bit_cast(unsigned short, (__bf16)b);
  return (unsigned)ua | ((unsigned)ub << 16);
}

__device__ __forceinline__ void stage16(const void* g, void* l) {
  __builtin_amdgcn_global_load_lds(
      (const __attribute__((address_space(1))) unsigned int*)g,
      (__attribute__((address_space(3))) unsigned int*)l, 16, 0, 0);
}

__device__ __forceinline__ float pick3(float a, float b, float c, int d) {
  return d == 0 ? a : (d == 1 ? b : c);
}

// sin/cos of v * pi * 2^f  ==  sin/cos(2*pi * rev), rev = v * 2^(f-1)  (HW revolutions, |rev|<256)
__device__ __forceinline__ float trig_rev(float rev, bool isCos) {
  return isCos ? __builtin_amdgcn_cosf(rev) : __builtin_amdgcn_sinf(rev);
}

// positional enc frags (cached once): frag s holds k2 = 16s + 8*q2 + j, j=0..7
// enc element k: d = k/20, f = (k%20)>>1, parity k&1 (kb even -> parity = j&1)
__device__ __forceinline__ void make_tp(bf16x8* tp, float x0, float x1, float x2, int q2) {
#pragma unroll
  for (int s = 0; s < 4; ++s) {
    bf16x8 r;
#pragma unroll
    for (int j = 0; j < 8; ++j) {
      const int kA = 16 * s + j;       // q2 == 0
      const int kB = 16 * s + 8 + j;   // q2 == 1
      const int dA = kA / 20, dB = kB / 20;
      const float scA = (float)(1 << ((kA % 20) >> 1)) * 0.5f;
      const float scB = (float)(1 << ((kB % 20) >> 1)) * 0.5f;
      const bool vA = kA < 60, vB = kB < 60;
      float v  = q2 ? pick3(x0, x1, x2, dB) : pick3(x0, x1, x2, dA);
      float sc = q2 ? scB : scA;
      bool ok  = q2 ? vB : vA;
      float t = trig_rev(v * sc, (j & 1) != 0);
      r[j] = (__bf16)(ok ? t : 0.0f);
    }
    tp[s] = r;
  }
}

// view enc frag sl (0..1): k2 = 16*sl + 8*q2 + j; element k: d = 3 + k/8, f = (k&7)>>1
__device__ __forceinline__ bf16x8 make_view_frag(float x3, float x4, float x5, int q2, int sl) {
  bf16x8 r;
#pragma unroll
  for (int j = 0; j < 8; ++j) {
    const int kA = 16 * sl + j;
    const int kB = 16 * sl + 8 + j;
    const int dA = kA >> 3, dB = kB >> 3;           // 0..2 -> x3..x5 (d-3)
    const bool vA = kA < 24, vB = kB < 24;
    const float sc = (float)(1 << (j >> 1)) * 0.5f; // f = (j&7)>>1 same both halves
    float v = q2 ? pick3(x3, x4, x5, dB) : pick3(x3, x4, x5, dA);
    bool ok = q2 ? vB : vA;
    float t = trig_rev(v * sc, (j & 1) != 0);
    r[j] = (__bf16)(ok ? t : 0.0f);
  }
  return r;
}

// 32x32x16 bf16 MFMA, operand swap: A = weights (m=feature), B = activations (n=point).
// C/D: col(point)=lane&31, row(feature)=(reg&3)+8*(reg>>2)+4*(lane>>5).
// T: row stride. SL: k-steps from sB. ST: trailing trig steps. TSRC: 1=cached pos, 2=view.
// NT: 32-feature tiles. OUTM: 0=sB, 1=d2_3 (sB feats + density/blend), 2=c_1 (rgb).
template <int T, int SL, int ST, int TSRC, int NT, bool RELU, int OUTM>
__device__ __forceinline__ void run_layer(const unsigned short* __restrict__ wsrc,
                                          unsigned short* __restrict__ sWt,
                                          unsigned short* __restrict__ sB,
                                          const bf16x8* tp,
                                          float x3, float x4, float x5,
                                          float* __restrict__ out, int base, int tid) {
  const int lane = tid & 63;
  const int w = tid >> 6;
  const int q2 = lane >> 5;
  const int l31 = lane & 31;
  const int tl = w & 1;
  const int pt = (w >> 1) * 32 + l31;
  const int sw = pt & 7;
  constexpr int S = SL + ST;

  __syncthreads();  // prev layer epilogue writes visible; prev sWt reads done

  // preload all B-frags (enables in-place sB update; separated from any
  // epilogue write by the post-stage barrier below)
  bf16x8 bf[S];
#pragma unroll
  for (int s = 0; s < SL; ++s)
    bf[s] = *(const bf16x8*)&sB[pt * 128 + (((2 * s + q2) ^ sw) << 3)];
#pragma unroll
  for (int j = 0; j < ST; ++j) {
    if (TSRC == 1) bf[SL + j] = tp[j];
    else           bf[SL + j] = make_view_frag(x3, x4, x5, q2, j);
  }

  constexpr int TPC_ = 512 / T;                   // tiles fitting 32768 B (tile = 64*T bytes)
  constexpr int TPC = TPC_ > NT ? NT : TPC_;
  constexpr int NCH = (NT + TPC - 1) / TPC;
#pragma unroll
  for (int c = 0; c < NCH; ++c) {
    const int tc = (NT - c * TPC) < TPC ? (NT - c * TPC) : TPC;
    if (c > 0) __syncthreads();                   // all waves done reading prev chunk
    {
      const uint4* __restrict__ src = (const uint4*)(wsrc + c * TPC * 32 * T);
      uint4* __restrict__ dstb = (uint4*)sWt;
      const int n16 = tc * 4 * T;                 // tc*32*T*2/16, always multiple of 512
      for (int i = tid; i < n16; i += 512)
        stage16(src + i, dstb + (i & ~63));
    }
    __syncthreads();                              // staged (vmcnt drained by barrier)
#pragma unroll
    for (int t0 = 0; t0 < TPC; t0 += 2) {
      const int t = t0 + tl;
      if (t < tc) {
        const int TILE = c * TPC + t;
        floatx16 acc;
#pragma unroll
        for (int i = 0; i < 16; ++i) acc[i] = 0.0f;
#pragma unroll
        for (int s = 0; s < S; ++s) {
          bf16x8 af = *(const bf16x8*)&sWt[(t * 32 + l31) * T + (((2 * s + q2) ^ (l31 & 7)) << 3)];
          acc = __builtin_amdgcn_mfma_f32_32x32x16_bf16(af, bf[s], acc, 0, 0, 0);
        }
        if (OUTM == 2) {
          if (q2 == 0) {  // rgb rows 0..2 = regs 0..2 at q2==0
            float* o = out + (size_t)(base + pt) * 5;
            o[0] = acc[0]; o[1] = acc[1]; o[2] = acc[2];
          }
        } else {
          if (OUTM == 0 || TILE < 4) {
#pragma unroll
            for (int g = 0; g < 4; ++g) {
              float a0 = acc[4 * g], a1 = acc[4 * g + 1], a2 = acc[4 * g + 2], a3 = acc[4 * g + 3];
              if (RELU) {
                a0 = fmaxf(a0, 0.f); a1 = fmaxf(a1, 0.f);
                a2 = fmaxf(a2, 0.f); a3 = fmaxf(a3, 0.f);
              }
              *(uint2*)&sB[pt * 128 + (((TILE * 4 + g) ^ sw) << 3) + 4 * q2] =
                  make_uint2(pk2(a0, a1), pk2(a2, a3));
            }
          }
          if (OUTM == 1 && q2 == 0) {
            if (TILE == 0) out[(size_t)(base + pt) * 5 + 3] = acc[0];           // density
            if (TILE == 4) out[(size_t)(base + pt) * 5 + 4] =                   // blending
                1.0f / (1.0f + __expf(-acc[0]));
          }
        }
      }
    }
  }
}

__global__ __launch_bounds__(512, 4) void nerf_main(const float* __restrict__ x,
                                                    const unsigned short* __restrict__ ws,
                                                    float* __restrict__ out) {
  __shared__ __align__(16) unsigned short sWt[16384];    // 32768 B weight stage
  __shared__ __align__(16) unsigned short sB[128 * 128]; // 32768 B activations (swizzled)

  const int tid = (int)threadIdx.x;
  const int base = (int)blockIdx.x * 128;
  const int lane = tid & 63;
  const int w = tid >> 6;
  const int q2 = lane >> 5;
  const int l31 = lane & 31;
  const int pt = (w >> 1) * 32 + l31;

  // per-lane x in registers (pt is fixed for this lane for the whole kernel)
  const float* xp = x + (size_t)(base + pt) * 6;
  float2 p01 = *(const float2*)xp;
  float2 p23 = *(const float2*)(xp + 2);
  float2 p45 = *(const float2*)(xp + 4);

  // positional trig frags computed ONCE (shared by d1_0 and d2_0)
  bf16x8 tp[4];
  make_tp(tp, p01.x, p01.y, p23.x, q2);

  //          T   SL ST TS NT relu  out
  run_layer< 64, 0, 4, 1, 4, true , 0>(ws + 0u,      sWt, sB, tp, p23.y, p45.x, p45.y, out, base, tid); // d1_0
  run_layer<128, 8, 0, 0, 4, true , 0>(ws + 8192u,   sWt, sB, tp, p23.y, p45.x, p45.y, out, base, tid); // d1_1
  run_layer<128, 8, 0, 0, 4, false, 0>(ws + 24576u,  sWt, sB, tp, p23.y, p45.x, p45.y, out, base, tid); // d1_2
  run_layer<192, 8, 4, 1, 4, true , 0>(ws + 40960u,  sWt, sB, tp, p23.y, p45.x, p45.y, out, base, tid); // d2_0
  run_layer<128, 8, 0, 0, 4, true , 0>(ws + 65536u,  sWt, sB, tp, p23.y, p45.x, p45.y, out, base, tid); // d2_1
  run_layer<128, 8, 0, 0, 4, true , 0>(ws + 81920u,  sWt, sB, tp, p23.y, p45.x, p45.y, out, base, tid); // d2_2
  run_layer<128, 8, 0, 0, 5, false, 1>(ws + 98304u,  sWt, sB, tp, p23.y, p45.x, p45.y, out, base, tid); // d2_3
  run_layer<192, 8, 2, 2, 4, true , 0>(ws + 118784u, sWt, sB, tp, p23.y, p45.x, p45.y, out, base, tid); // c_0
  run_layer<128, 8, 0, 0, 1, false, 2>(ws + 143360u, sWt, sB, tp, p23.y, p45.x, p45.y, out, base, tid); // c_1
}

extern "C" void kernel_launch(void* const* d_in, const int* in_sizes, int n_in,
                              void* d_out, int out_size, void* d_ws, size_t ws_size,
                              hipStream_t stream) {
  (void)n_in; (void)out_size; (void)ws_size;
  const float* x = (const float*)d_in[0];
  SrcPtrs sp;
  for (int i = 0; i < 9; ++i) sp.p[i] = (const float*)d_in[1 + i];
  unsigned short* ws = (unsigned short*)d_ws;
  float* out = (float*)d_out;
  const int N = in_sizes[0] / 6;

  prep_zero<<<72, 256, 0, stream>>>(ws);
  prep_fill<<<144, 256, 0, stream>>>(sp, ws);
  nerf_main<<<N / 128, 512, 0, stream>>>(x, ws, out);
}

// Round 4
// 394.037 us; speedup vs baseline: 1.3150x; 1.0758x over previous
//
#include <hip/hip_runtime.h>
#include <cstdint>
#include <cstddef>

typedef __attribute__((ext_vector_type(8))) __bf16 bf16x8;
typedef __attribute__((ext_vector_type(16))) float floatx16;

struct SrcPtrs { const float* p[9]; };

// ---------------- weight workspace layout (bf16 elems) ----------------
// Rows = output features (A-operand, m). Row length T shorts, 16B-chunk
// XOR-swizzled: logical short kk lives at phys ((kk>>3 ^ (row&7))<<3)|(kk&7).
// m  mat    K    N     T    rows  off      k-remap
// 0  Wd1_0  60   128   64   128   0
// 1  Wd1_1  128  128   128  128   8192
// 2  Wd1_2  128  128   128  128   24576
// 3  Wd2_0  188  128   192  128   40960    k<60 -> 128+k (enc tail), k>=60 -> k-60 (part1 first)
// 4  Wd2_1  128  128   128  128   65536
// 5  Wd2_2  128  128   128  128   81920
// 6  Wd2_3  128  129   128  160   98304    col0 -> row128 (blend), col j+1 -> row j
// 7  Wc_0   152  128   192  128   118784   k<24 -> 128+k (view tail), k>=24 -> k-24 (feature first)
// 8  Wc_1   128  3     128  32    143360   rows 3..31 zero

__global__ void prep_zero(unsigned short* __restrict__ ws) {
  uint4* p = (uint4*)ws;
  const int n = 147456 / 8;
  for (int i = blockIdx.x * blockDim.x + threadIdx.x; i < n; i += gridDim.x * blockDim.x)
    p[i] = make_uint4(0u, 0u, 0u, 0u);
}

__global__ void prep_fill(SrcPtrs sp, unsigned short* __restrict__ ws) {
  const int m  = blockIdx.x >> 4;
  const int sl = blockIdx.x & 15;
  const int K[9]  = {60, 128, 128, 188, 128, 128, 128, 152, 128};
  const int N[9]  = {128, 128, 128, 128, 128, 128, 129, 128, 3};
  const int TT[9] = {64, 128, 128, 192, 128, 128, 128, 192, 128};
  const unsigned OFF[9] = {0u, 8192u, 24576u, 40960u, 65536u, 81920u, 98304u, 118784u, 143360u};
  const int Km = K[m], Nm = N[m], Tm = TT[m];
  const float* __restrict__ src = sp.p[m];
  unsigned short* __restrict__ dst = ws + OFF[m];
  const int tot = Km * Nm;
  for (int i = sl * 256 + (int)threadIdx.x; i < tot; i += 16 * 256) {
    int k = i / Nm;
    int n = i - k * Nm;
    int kk = k, row = n;
    if (m == 3) kk = (k < 60) ? 128 + k : k - 60;
    if (m == 7) kk = (k < 24) ? 128 + k : k - 24;
    if (m == 6) row = (n == 0) ? 128 : n - 1;
    int c = (kk >> 3) ^ (row & 7);
    int phys = (c << 3) | (kk & 7);
    dst[row * Tm + phys] = __builtin_bit_cast(unsigned short, (__bf16)src[i]);
  }
}

// ---------------- main fused kernel ----------------

__device__ __forceinline__ unsigned pk2(float a, float b) {
  unsigned short ua = __builtin_bit_cast(unsigned short, (__bf16)a);
  unsigned short ub = __builtin_bit_cast(unsigned short, (__bf16)b);
  return (unsigned)ua | ((unsigned)ub << 16);
}

__device__ __forceinline__ void stage16(const void* g, void* l) {
  __builtin_amdgcn_global_load_lds(
      (const __attribute__((address_space(1))) unsigned int*)g,
      (__attribute__((address_space(3))) unsigned int*)l, 16, 0, 0);
}

// sin/cos of v * pi * 2^f  ==  sin/cos(2*pi * rev), rev = v * 2^(f-1)  (HW revolutions)
// KIND 0: positional enc, elements k2 = 16*sl + 8*q2 + j: d=k2/20, f=(k2%20)>>1, valid k2<60
// KIND 1: view enc: d=3+k2/8, f=(k2%8)>>1, valid k2<24
template <int KIND>
__device__ __forceinline__ bf16x8 trig_frag(const float (&x)[6], int q2, int sl) {
  bf16x8 r;
#pragma unroll
  for (int j = 0; j < 8; ++j) {
    const int kA = 16 * sl + j;       // q2 == 0
    const int kB = 16 * sl + 8 + j;   // q2 == 1
    int dA, dB; float scA, scB; bool vA, vB;
    if (KIND == 0) {
      vA = kA < 60; vB = kB < 60;
      dA = kA / 20; dB = kB / 20;
      scA = (float)(1 << ((kA % 20) >> 1)) * 0.5f;
      scB = (float)(1 << ((kB % 20) >> 1)) * 0.5f;
    } else {
      vA = kA < 24; vB = kB < 24;
      dA = 3 + (kA >> 3); dB = 3 + (kB >> 3);
      scA = (float)(1 << ((kA & 7) >> 1)) * 0.5f;
      scB = (float)(1 << ((kB & 7) >> 1)) * 0.5f;
    }
    float v  = q2 ? x[dB] : x[dA];
    float sc = q2 ? scB : scA;
    bool ok  = q2 ? vB : vA;
    float rev = v * sc;
    float t = (j & 1) ? __builtin_amdgcn_cosf(rev) : __builtin_amdgcn_sinf(rev);
    r[j] = (__bf16)(ok ? t : 0.0f);
  }
  return r;
}

// 32x32x16 bf16 MFMA, A = weights (m=feature), B = activations (n=point).
// Wave owns 2 m-tiles (64 points) x ALL n-tiles -> each A ds_read feeds 2 MFMAs,
// activations live in registers across layers (pkv), exchanged lane<->lane^32.
// pkv[m][j] (j=0..15): feats 8j + 4*q2 + {0..3} of point (base+64w+32m+l31), bf16-packed.
// B-frag s (k=16s+8q2+j): lo = q2'=0 holder's group 2s+q2, hi = q2'=1 holder's.
template <int T, int SL, int ST, int KIND, int NT, bool RELU, int OUTM, int ROWS>
__device__ __forceinline__ void run_layer(const unsigned short* __restrict__ wsrc,
                                          unsigned short* __restrict__ sWt,
                                          uint2 (&pkv)[2][16],
                                          const float (&x0)[6], const float (&x1)[6],
                                          float* __restrict__ out, int base, int tid) {
  const int lane = tid & 63;
  const int w = tid >> 6;
  const int q2 = lane >> 5;
  const int l31 = lane & 31;
  constexpr int S = SL + ST;

  __syncthreads();  // all waves done reading sWt (previous layer)

  // stage whole layer into LDS (async; overlapped by B-build below)
  {
    const uint4* __restrict__ src = (const uint4*)wsrc;
    uint4* __restrict__ dst = (uint4*)sWt;
    constexpr int NI = (ROWS * T / 8) / 256;
#pragma unroll
    for (int i = 0; i < NI; ++i)
      stage16(src + i * 256 + tid, dst + ((i * 256 + tid) & ~63));
  }

  // build B-fragments from register-resident packed activations (+ trig tails)
  bf16x8 bf[2][S > 0 ? S : 1];
#pragma unroll
  for (int s = 0; s < SL; ++s) {
#pragma unroll
    for (int m = 0; m < 2; ++m) {
      uint2 p0 = pkv[m][2 * s], p1 = pkv[m][2 * s + 1];
      unsigned sh0x = __shfl_xor(p0.x, 32, 64);
      unsigned sh0y = __shfl_xor(p0.y, 32, 64);
      unsigned sh1x = __shfl_xor(p1.x, 32, 64);
      unsigned sh1y = __shfl_xor(p1.y, 32, 64);
      uint4 u = make_uint4(q2 ? sh1x : p0.x, q2 ? sh1y : p0.y,
                           q2 ? p1.x : sh0x, q2 ? p1.y : sh0y);
      bf[m][s] = __builtin_bit_cast(bf16x8, u);
    }
  }
#pragma unroll
  for (int j = 0; j < ST; ++j) {
    bf[0][SL + j] = trig_frag<KIND>(x0, q2, j);
    bf[1][SL + j] = trig_frag<KIND>(x1, q2, j);
  }

  __syncthreads();  // staging complete

  const int pt0 = base + w * 64 + l31;
  const int pt1 = pt0 + 32;
#pragma unroll
  for (int t = 0; t < NT; ++t) {
    floatx16 a0, a1;
#pragma unroll
    for (int i = 0; i < 16; ++i) { a0[i] = 0.0f; a1[i] = 0.0f; }
#pragma unroll
    for (int s = 0; s < S; ++s) {
      bf16x8 A = *(const bf16x8*)&sWt[(t * 32 + l31) * T + (((2 * s + q2) ^ (l31 & 7)) << 3)];
      a0 = __builtin_amdgcn_mfma_f32_32x32x16_bf16(A, bf[0][s], a0, 0, 0, 0);
      a1 = __builtin_amdgcn_mfma_f32_32x32x16_bf16(A, bf[1][s], a1, 0, 0, 0);
    }
    if (OUTM == 2) {
      if (q2 == 0) {  // rgb = rows 0..2 -> regs 0..2 at q2==0
        float* o0 = out + (size_t)pt0 * 5;
        o0[0] = a0[0]; o0[1] = a0[1]; o0[2] = a0[2];
        float* o1 = out + (size_t)pt1 * 5;
        o1[0] = a1[0]; o1[1] = a1[1]; o1[2] = a1[2];
      }
    } else {
      if (OUTM == 0 || t < 4) {
#pragma unroll
        for (int gg = 0; gg < 4; ++gg) {
          float b0 = a0[4 * gg], b1 = a0[4 * gg + 1], b2 = a0[4 * gg + 2], b3 = a0[4 * gg + 3];
          float c0 = a1[4 * gg], c1 = a1[4 * gg + 1], c2 = a1[4 * gg + 2], c3 = a1[4 * gg + 3];
          if (RELU) {
            b0 = fmaxf(b0, 0.f); b1 = fmaxf(b1, 0.f); b2 = fmaxf(b2, 0.f); b3 = fmaxf(b3, 0.f);
            c0 = fmaxf(c0, 0.f); c1 = fmaxf(c1, 0.f); c2 = fmaxf(c2, 0.f); c3 = fmaxf(c3, 0.f);
          }
          pkv[0][4 * t + gg] = make_uint2(pk2(b0, b1), pk2(b2, b3));
          pkv[1][4 * t + gg] = make_uint2(pk2(c0, c1), pk2(c2, c3));
        }
      }
      if (OUTM == 1 && q2 == 0) {
        if (t == 0) {  // density = feature[:,0] = row 0 (f32, pre-rounding)
          out[(size_t)pt0 * 5 + 3] = a0[0];
          out[(size_t)pt1 * 5 + 3] = a1[0];
        }
        if (t == 4) {  // blending = sigmoid(row 128)
          out[(size_t)pt0 * 5 + 4] = 1.0f / (1.0f + __expf(-a0[0]));
          out[(size_t)pt1 * 5 + 4] = 1.0f / (1.0f + __expf(-a1[0]));
        }
      }
    }
  }
}

__global__ __launch_bounds__(256, 2) void nerf_main(const float* __restrict__ x,
                                                    const unsigned short* __restrict__ ws,
                                                    float* __restrict__ out) {
  __shared__ __align__(16) unsigned short sWt[24576];  // 49152 B: one full layer of weights

  const int tid = (int)threadIdx.x;
  const int base = (int)blockIdx.x * 256;
  const int w = tid >> 6;
  const int l31 = tid & 31;
  const int pt0 = base + w * 64 + l31;

  float x0[6], x1[6];
  {
    const float* a = x + (size_t)pt0 * 6;
    const float* b = x + (size_t)(pt0 + 32) * 6;
#pragma unroll
    for (int c = 0; c < 3; ++c) {
      float2 u = *(const float2*)(a + 2 * c);
      float2 v = *(const float2*)(b + 2 * c);
      x0[2 * c] = u.x; x0[2 * c + 1] = u.y;
      x1[2 * c] = v.x; x1[2 * c + 1] = v.y;
    }
  }

  uint2 pkv[2][16];
#pragma unroll
  for (int m = 0; m < 2; ++m)
#pragma unroll
    for (int j = 0; j < 16; ++j) pkv[m][j] = make_uint2(0u, 0u);

  //          T   SL ST K  NT relu  out ROWS
  run_layer< 64, 0, 4, 0, 4, true , 0, 128>(ws + 0u,      sWt, pkv, x0, x1, out, base, tid); // d1_0
  run_layer<128, 8, 0, 0, 4, true , 0, 128>(ws + 8192u,   sWt, pkv, x0, x1, out, base, tid); // d1_1
  run_layer<128, 8, 0, 0, 4, false, 0, 128>(ws + 24576u,  sWt, pkv, x0, x1, out, base, tid); // d1_2 -> part1
  run_layer<192, 8, 4, 0, 4, true , 0, 128>(ws + 40960u,  sWt, pkv, x0, x1, out, base, tid); // d2_0 [part1|enc_pos]
  run_layer<128, 8, 0, 0, 4, true , 0, 128>(ws + 65536u,  sWt, pkv, x0, x1, out, base, tid); // d2_1
  run_layer<128, 8, 0, 0, 4, true , 0, 128>(ws + 81920u,  sWt, pkv, x0, x1, out, base, tid); // d2_2
  run_layer<128, 8, 0, 0, 5, false, 1, 160>(ws + 98304u,  sWt, pkv, x0, x1, out, base, tid); // d2_3 -> feat,dens,blend
  run_layer<192, 8, 2, 1, 4, true , 0, 128>(ws + 118784u, sWt, pkv, x0, x1, out, base, tid); // c_0 [feature|enc_view]
  run_layer<128, 8, 0, 0, 1, false, 2,  32>(ws + 143360u, sWt, pkv, x0, x1, out, base, tid); // c_1 -> rgb
}

extern "C" void kernel_launch(void* const* d_in, const int* in_sizes, int n_in,
                              void* d_out, int out_size, void* d_ws, size_t ws_size,
                              hipStream_t stream) {
  (void)n_in; (void)out_size; (void)ws_size;
  const float* x = (const float*)d_in[0];
  SrcPtrs sp;
  for (int i = 0; i < 9; ++i) sp.p[i] = (const float*)d_in[1 + i];
  unsigned short* ws = (unsigned short*)d_ws;
  float* out = (float*)d_out;
  const int N = in_sizes[0] / 6;

  prep_zero<<<72, 256, 0, stream>>>(ws);
  prep_fill<<<144, 256, 0, stream>>>(sp, ws);
  nerf_main<<<N / 256, 256, 0, stream>>>(x, ws, out);
}

// Round 5
// 375.029 us; speedup vs baseline: 1.3816x; 1.0507x over previous
//
#include <hip/hip_runtime.h>
#include <cstdint>
#include <cstddef>

typedef __attribute__((ext_vector_type(8))) __bf16 bf16x8;
typedef __attribute__((ext_vector_type(16))) float floatx16;

struct SrcPtrs { const float* p[9]; };

// ---------------- weight workspace layout (bf16 elems) ----------------
// Rows = output features (A-operand, m). Row length T shorts, 16B-chunk
// XOR-swizzled: logical short kk lives at phys ((kk>>3 ^ (row&7))<<3)|(kk&7).
// m  mat    K    N     T    rows  off      k-remap
// 0  Wd1_0  60   128   64   128   0
// 1  Wd1_1  128  128   128  128   8192
// 2  Wd1_2  128  128   128  128   24576
// 3  Wd2_0  188  128   192  128   40960    k<60 -> 128+k (enc tail), k>=60 -> k-60 (part1 first)
// 4  Wd2_1  128  128   128  128   65536
// 5  Wd2_2  128  128   128  128   81920
// 6  Wd2_3  128  129   128  160   98304    col0 -> row128 (blend), col j+1 -> row j
// 7  Wc_0   152  128   192  128   118784   k<24 -> 128+k (view tail), k>=24 -> k-24 (feature first)
// 8  Wc_1   128  3     128  32    143360   rows 3..31 zero

__global__ void prep_zero(unsigned short* __restrict__ ws) {
  uint4* p = (uint4*)ws;
  const int n = 147456 / 8;
  for (int i = blockIdx.x * blockDim.x + threadIdx.x; i < n; i += gridDim.x * blockDim.x)
    p[i] = make_uint4(0u, 0u, 0u, 0u);
}

__global__ void prep_fill(SrcPtrs sp, unsigned short* __restrict__ ws) {
  const int m  = blockIdx.x >> 4;
  const int sl = blockIdx.x & 15;
  const int K[9]  = {60, 128, 128, 188, 128, 128, 128, 152, 128};
  const int N[9]  = {128, 128, 128, 128, 128, 128, 129, 128, 3};
  const int TT[9] = {64, 128, 128, 192, 128, 128, 128, 192, 128};
  const unsigned OFF[9] = {0u, 8192u, 24576u, 40960u, 65536u, 81920u, 98304u, 118784u, 143360u};
  const int Km = K[m], Nm = N[m], Tm = TT[m];
  const float* __restrict__ src = sp.p[m];
  unsigned short* __restrict__ dst = ws + OFF[m];
  const int tot = Km * Nm;
  for (int i = sl * 256 + (int)threadIdx.x; i < tot; i += 16 * 256) {
    int k = i / Nm;
    int n = i - k * Nm;
    int kk = k, row = n;
    if (m == 3) kk = (k < 60) ? 128 + k : k - 60;
    if (m == 7) kk = (k < 24) ? 128 + k : k - 24;
    if (m == 6) row = (n == 0) ? 128 : n - 1;
    int c = (kk >> 3) ^ (row & 7);
    int phys = (c << 3) | (kk & 7);
    dst[row * Tm + phys] = __builtin_bit_cast(unsigned short, (__bf16)src[i]);
  }
}

// ---------------- main fused kernel ----------------

#if defined(__has_builtin)
#if __has_builtin(__builtin_amdgcn_permlane32_swap)
#define HAVE_PLSWAP 1
#endif
#endif
#ifndef HAVE_PLSWAP
#define HAVE_PLSWAP 0
#endif

__device__ __forceinline__ unsigned pk2(float a, float b) {
  unsigned short ua = __builtin_bit_cast(unsigned short, (__bf16)a);
  unsigned short ub = __builtin_bit_cast(unsigned short, (__bf16)b);
  return (unsigned)ua | ((unsigned)ub << 16);
}

__device__ __forceinline__ void stage16(const void* g, void* l) {
  __builtin_amdgcn_global_load_lds(
      (const __attribute__((address_space(1))) unsigned int*)g,
      (__attribute__((address_space(3))) unsigned int*)l, 16, 0, 0);
}

// (lo, hi) per lane: lo = q2==0 ? own a : partner's b ; hi = q2==0 ? partner's a : own b
// == v_permlane32_swap_b32(a, b): a' = {a.lo32, b.lo32}, b' = {a.hi32, b.hi32}
__device__ __forceinline__ void half_swap(unsigned a, unsigned b, int q2,
                                          unsigned& lo, unsigned& hi) {
#if HAVE_PLSWAP
  auto r = __builtin_amdgcn_permlane32_swap(a, b, false, false);
  lo = r[0]; hi = r[1];
#else
  unsigned sa = __shfl_xor(a, 32, 64);
  unsigned sb = __shfl_xor(b, 32, 64);
  lo = q2 ? sb : a;
  hi = q2 ? b : sa;
#endif
}

// sin/cos of v * pi * 2^f == sin/cos(2*pi*rev), rev = v * 2^(f-1) (HW revolutions)
// KIND 0: positional enc, k2 = 16*sl + 8*q2 + j: d=k2/20, f=(k2%20)>>1, valid k2<60
// KIND 1: view enc: d=3+k2/8, f=(k2%8)>>1, valid k2<24
template <int KIND>
__device__ __forceinline__ bf16x8 trig_frag(const float (&x)[6], int q2, int sl) {
  bf16x8 r;
#pragma unroll
  for (int j = 0; j < 8; ++j) {
    const int kA = 16 * sl + j;       // q2 == 0
    const int kB = 16 * sl + 8 + j;   // q2 == 1
    int dA, dB; float scA, scB; bool vA, vB;
    if (KIND == 0) {
      vA = kA < 60; vB = kB < 60;
      dA = kA / 20; dB = kB / 20;
      scA = (float)(1 << ((kA % 20) >> 1)) * 0.5f;
      scB = (float)(1 << ((kB % 20) >> 1)) * 0.5f;
    } else {
      vA = kA < 24; vB = kB < 24;
      dA = 3 + (kA >> 3); dB = 3 + (kB >> 3);
      scA = (float)(1 << ((kA & 7) >> 1)) * 0.5f;
      scB = (float)(1 << ((kB & 7) >> 1)) * 0.5f;
    }
    float v  = q2 ? x[dB] : x[dA];
    float sc = q2 ? scB : scA;
    bool ok  = q2 ? vB : vA;
    float rev = v * sc;
    float t = (j & 1) ? __builtin_amdgcn_cosf(rev) : __builtin_amdgcn_sinf(rev);
    r[j] = (__bf16)(ok ? t : 0.0f);
  }
  return r;
}

// 32x32x16 bf16 MFMA, A = weights (m=feature), B = activations (n=point).
// Wave owns 2 m-tiles (64 points) x ALL n-tiles; activations register-resident
// (pkv), half-exchanged via permlane32_swap. Weights ping-pong through 2x16KB
// LDS buffers; each chunk's staging is issued one full compute-phase before
// the barrier that drains it (cross-layer software pipeline).
// pkv[m][j]: feats 8j+4q2+{0..3} of point (base+64w+32m+l31), bf16-packed.
// T: row stride. SL: k-steps from pkv. ST: trig k-steps. TSRC: 1=pkt(pos), 2=view.
// NT: 32-feature tiles. CT: tiles/chunk. PP0: entry buffer parity.
// OUTM: 0=pkv, 1=d2_3 (pkv feats + density/blend), 2=c_1 (rgb).
template <int T, int SL, int ST, int TSRC, int NT, int CT, int PP0, bool RELU, int OUTM>
__device__ __forceinline__ void run_layer(const unsigned short* __restrict__ wsrc,
                                          const unsigned short* __restrict__ nsrc, int nbytes,
                                          unsigned short* __restrict__ sWt,
                                          uint2 (&pkv)[2][16],
                                          const bf16x8 (&pkt)[2][4],
                                          const float (&x0)[6], const float (&x1)[6],
                                          float* __restrict__ out, int base, int tid) {
  const int lane = tid & 63;
  const int w = tid >> 6;
  const int q2 = lane >> 5;
  const int l31 = lane & 31;
  const int swz = l31 & 7;
  constexpr int S = SL + ST;

  // build B-fragments (registers only; overlaps the in-flight staging of chunk 0)
  bf16x8 bf[2][S];
#pragma unroll
  for (int s = 0; s < SL; ++s) {
#pragma unroll
    for (int m = 0; m < 2; ++m) {
      uint2 p0 = pkv[m][2 * s], p1 = pkv[m][2 * s + 1];
      unsigned w0, w2, w1, w3;
      half_swap(p0.x, p1.x, q2, w0, w2);
      half_swap(p0.y, p1.y, q2, w1, w3);
      uint4 u = make_uint4(w0, w1, w2, w3);
      bf[m][s] = __builtin_bit_cast(bf16x8, u);
    }
  }
#pragma unroll
  for (int j = 0; j < ST; ++j) {
    if (TSRC == 1) {
      bf[0][SL + j] = pkt[0][j];
      bf[1][SL + j] = pkt[1][j];
    } else {
      bf[0][SL + j] = trig_frag<1>(x0, q2, j);
      bf[1][SL + j] = trig_frag<1>(x1, q2, j);
    }
  }

  const int pt0 = base + w * 64 + l31;
  const int pt1 = pt0 + 32;

  constexpr int NC = (NT + CT - 1) / CT;
#pragma unroll
  for (int c = 0; c < NC; ++c) {
    const int pp = PP0 ^ (c & 1);
    __syncthreads();  // drains chunk-c staging (issued a full compute-phase ago);
                      // all waves done reading buf[pp^1]
    // prefetch next chunk (or next layer's first chunk) into the other buffer
    {
      const unsigned short* src;
      int bytes;
      if (c + 1 < NC) {
        src = wsrc + (c + 1) * CT * 32 * T;
        bytes = ((NT - (c + 1) * CT) < CT ? (NT - (c + 1) * CT) : CT) * 64 * T;
      } else {
        src = nsrc;
        bytes = nbytes;
      }
      const uint4* s4 = (const uint4*)src;
      uint4* dst = (uint4*)(sWt + (pp ^ 1) * 8192);
      const int n16 = bytes / 16;
      for (int i = tid; i < n16; i += 256)
        stage16(s4 + i, dst + (i & ~63));
    }
    // compute chunk c from buf[pp]
    const unsigned short* bufp = sWt + pp * 8192;
#pragma unroll
    for (int tt = 0; tt < CT; ++tt) {
      if (c * CT + tt < NT) {
        const int TILE = c * CT + tt;
        floatx16 a0, a1;
#pragma unroll
        for (int i = 0; i < 16; ++i) { a0[i] = 0.0f; a1[i] = 0.0f; }
#pragma unroll
        for (int s = 0; s < S; ++s) {
          bf16x8 A = *(const bf16x8*)&bufp[(tt * 32 + l31) * T + (((2 * s + q2) ^ swz) << 3)];
          a0 = __builtin_amdgcn_mfma_f32_32x32x16_bf16(A, bf[0][s], a0, 0, 0, 0);
          a1 = __builtin_amdgcn_mfma_f32_32x32x16_bf16(A, bf[1][s], a1, 0, 0, 0);
        }
        if (OUTM == 2) {
          if (q2 == 0) {  // rgb = rows 0..2 -> regs 0..2 at q2==0
            float* o0 = out + (size_t)pt0 * 5;
            o0[0] = a0[0]; o0[1] = a0[1]; o0[2] = a0[2];
            float* o1 = out + (size_t)pt1 * 5;
            o1[0] = a1[0]; o1[1] = a1[1]; o1[2] = a1[2];
          }
        } else {
          if (OUTM == 0 || TILE < 4) {
#pragma unroll
            for (int gg = 0; gg < 4; ++gg) {
              float b0 = a0[4 * gg], b1 = a0[4 * gg + 1], b2 = a0[4 * gg + 2], b3 = a0[4 * gg + 3];
              float c0 = a1[4 * gg], c1 = a1[4 * gg + 1], c2 = a1[4 * gg + 2], c3 = a1[4 * gg + 3];
              if (RELU) {
                b0 = fmaxf(b0, 0.f); b1 = fmaxf(b1, 0.f); b2 = fmaxf(b2, 0.f); b3 = fmaxf(b3, 0.f);
                c0 = fmaxf(c0, 0.f); c1 = fmaxf(c1, 0.f); c2 = fmaxf(c2, 0.f); c3 = fmaxf(c3, 0.f);
              }
              pkv[0][4 * TILE + gg] = make_uint2(pk2(b0, b1), pk2(b2, b3));
              pkv[1][4 * TILE + gg] = make_uint2(pk2(c0, c1), pk2(c2, c3));
            }
          }
          if (OUTM == 1 && q2 == 0) {
            if (TILE == 0) {  // density = feature[:,0] = row 0 (f32, pre-rounding)
              out[(size_t)pt0 * 5 + 3] = a0[0];
              out[(size_t)pt1 * 5 + 3] = a1[0];
            }
            if (TILE == 4) {  // blending = sigmoid(row 128)
              out[(size_t)pt0 * 5 + 4] = 1.0f / (1.0f + __expf(-a0[0]));
              out[(size_t)pt1 * 5 + 4] = 1.0f / (1.0f + __expf(-a1[0]));
            }
          }
        }
      }
    }
  }
}

__global__ __launch_bounds__(256, 2) void nerf_main(const float* __restrict__ x,
                                                    const unsigned short* __restrict__ ws,
                                                    float* __restrict__ out) {
  __shared__ __align__(16) unsigned short sWt[2 * 8192];  // 2 x 16 KB ping-pong weight buffers

  const int tid = (int)threadIdx.x;
  const int base = (int)blockIdx.x * 256;
  const int lane = tid & 63;
  const int w = tid >> 6;
  const int q2 = lane >> 5;
  const int l31 = lane & 31;
  const int pt0 = base + w * 64 + l31;

  // kick off staging of layer 0 chunk 0 (16 KB) into buf0 immediately
  {
    const uint4* s4 = (const uint4*)ws;
    uint4* dst = (uint4*)sWt;
#pragma unroll
    for (int i = 0; i < 4; ++i)
      stage16(s4 + i * 256 + tid, dst + ((i * 256 + tid) & ~63));
  }

  // per-lane x in registers (pt fixed per lane for whole kernel)
  float x0[6], x1[6];
  {
    const float* a = x + (size_t)pt0 * 6;
    const float* b = x + (size_t)(pt0 + 32) * 6;
#pragma unroll
    for (int c = 0; c < 3; ++c) {
      float2 u = *(const float2*)(a + 2 * c);
      float2 v = *(const float2*)(b + 2 * c);
      x0[2 * c] = u.x; x0[2 * c + 1] = u.y;
      x1[2 * c] = v.x; x1[2 * c + 1] = v.y;
    }
  }

  // positional trig frags computed ONCE (used by d1_0 and d2_0); overlaps staging
  bf16x8 pkt[2][4];
#pragma unroll
  for (int sl = 0; sl < 4; ++sl) {
    pkt[0][sl] = trig_frag<0>(x0, q2, sl);
    pkt[1][sl] = trig_frag<0>(x1, q2, sl);
  }

  uint2 pkv[2][16];
#pragma unroll
  for (int m = 0; m < 2; ++m)
#pragma unroll
    for (int j = 0; j < 16; ++j) pkv[m][j] = make_uint2(0u, 0u);

  //          T   SL ST TS NT CT PP relu  out        wsrc           next_src       next_bytes
  run_layer< 64, 0, 4, 1, 4, 4, 0, true , 0>(ws + 0u,      ws + 8192u,   16384, sWt, pkv, pkt, x0, x1, out, base, tid); // d1_0
  run_layer<128, 8, 0, 0, 4, 2, 1, true , 0>(ws + 8192u,   ws + 24576u,  16384, sWt, pkv, pkt, x0, x1, out, base, tid); // d1_1
  run_layer<128, 8, 0, 0, 4, 2, 1, false, 0>(ws + 24576u,  ws + 40960u,  12288, sWt, pkv, pkt, x0, x1, out, base, tid); // d1_2 -> part1
  run_layer<192, 8, 4, 1, 4, 1, 1, true , 0>(ws + 40960u,  ws + 65536u,  16384, sWt, pkv, pkt, x0, x1, out, base, tid); // d2_0 [part1|enc_pos]
  run_layer<128, 8, 0, 0, 4, 2, 1, true , 0>(ws + 65536u,  ws + 81920u,  16384, sWt, pkv, pkt, x0, x1, out, base, tid); // d2_1
  run_layer<128, 8, 0, 0, 4, 2, 1, true , 0>(ws + 81920u,  ws + 98304u,  16384, sWt, pkv, pkt, x0, x1, out, base, tid); // d2_2
  run_layer<128, 8, 0, 0, 5, 2, 1, false, 1>(ws + 98304u,  ws + 118784u, 12288, sWt, pkv, pkt, x0, x1, out, base, tid); // d2_3
  run_layer<192, 8, 2, 2, 4, 1, 0, true , 0>(ws + 118784u, ws + 143360u,  8192, sWt, pkv, pkt, x0, x1, out, base, tid); // c_0 [feature|enc_view]
  run_layer<128, 8, 0, 0, 1, 1, 0, false, 2>(ws + 143360u, (const unsigned short*)nullptr, 0, sWt, pkv, pkt, x0, x1, out, base, tid); // c_1 -> rgb
}

extern "C" void kernel_launch(void* const* d_in, const int* in_sizes, int n_in,
                              void* d_out, int out_size, void* d_ws, size_t ws_size,
                              hipStream_t stream) {
  (void)n_in; (void)out_size; (void)ws_size;
  const float* x = (const float*)d_in[0];
  SrcPtrs sp;
  for (int i = 0; i < 9; ++i) sp.p[i] = (const float*)d_in[1 + i];
  unsigned short* ws = (unsigned short*)d_ws;
  float* out = (float*)d_out;
  const int N = in_sizes[0] / 6;

  prep_zero<<<72, 256, 0, stream>>>(ws);
  prep_fill<<<144, 256, 0, stream>>>(sp, ws);
  nerf_main<<<N / 256, 256, 0, stream>>>(x, ws, out);
}